// Round 5
// baseline (220.656 us; speedup 1.0000x reference)
//
#include <hip/hip_runtime.h>
#include <hip/hip_bf16.h>

// SAGAN self-attention, B=4, C=256, N=4096, Cqk=16, fp32 I/O.
//  K0 cast_w    : Wbf[288][256] bf16  (rows 0-15 Wq, 16-31 Wk, 32-287 Wv)
//  K1 proj_fused: per (n-tile 128, m-half 144, b): W-half + x-tile staged in
//                 swizzled LDS once; MFMA; LDS-overlay epilogue -> coalesced
//                 stores of qT/kT[b][n][24] and vbf[b][c][n].
//  K2 attn      : per (b, 64-m, 128-c half): loop 64 n-tiles:
//                 S = q^T k (MFMA), e=exp(S); den += sum e; num += V @ e.
//                 V,q global->reg prefetch (L2-resident); only P in LDS
//                 (dbuf, XOR-swizzled); one raw s_barrier per tile.
//                 2 blocks/CU; setprio around PV. out = x + gamma*num/den.

constexpr int B_ = 4;
constexpr int C_ = 256;
constexpr int N_ = 4096;
constexpr int NT = 64;

typedef short   bf16x8  __attribute__((ext_vector_type(8)));
typedef short   short4v __attribute__((ext_vector_type(4)));
typedef unsigned short ushort8v __attribute__((ext_vector_type(8)));
typedef float   f32x4   __attribute__((ext_vector_type(4)));

__device__ __forceinline__ unsigned short f2bf(float f) {
  __hip_bfloat16 h = __float2bfloat16(f);
  return *reinterpret_cast<unsigned short*>(&h);
}

// ---------------------------------------------------------------- K0: W -> bf16
__global__ __launch_bounds__(256) void cast_w_kernel(
    const float* __restrict__ Wq, const float* __restrict__ Wk,
    const float* __restrict__ Wv, unsigned short* __restrict__ Wbf) {
  const int f = (blockIdx.x * 256 + threadIdx.x) * 8;
  const float* src;
  if (f < 4096)      src = Wq + f;
  else if (f < 8192) src = Wk + (f - 4096);
  else               src = Wv + (f - 8192);
  f32x4 a = *(const f32x4*)src;
  f32x4 c = *(const f32x4*)(src + 4);
  ushort8v o;
#pragma unroll
  for (int e = 0; e < 4; ++e) { o[e] = f2bf(a[e]); o[4 + e] = f2bf(c[e]); }
  *(ushort8v*)&Wbf[f] = o;
}

// ---------------------------------------------------------------- K1: fused projections
__global__ __launch_bounds__(512) void proj_fused_kernel(
    const float* __restrict__ x, const unsigned short* __restrict__ Wbf,
    const float* __restrict__ bq, const float* __restrict__ bk,
    const float* __restrict__ bv,
    unsigned short* __restrict__ qT, unsigned short* __restrict__ kT,
    unsigned short* __restrict__ vbf) {
  // xsm [128 n][256 k] bf16 swizzled (64 KB) | Wsm [144 m][256 k] bf16 swizzled (72 KB)
  __shared__ __align__(16) char smem[139264];
  char* xsm = smem;
  char* Wsm = smem + 65536;
  const int tid = threadIdx.x;
  const int n0 = blockIdx.x << 7;
  const int mh = blockIdx.y;            // m-half: rows [144*mh, 144*mh+144)
  const int b  = blockIdx.z;
  const int ln = tid & 63, w = tid >> 6;
  const int g  = ln >> 4, li = ln & 15;

  { // stage W-half: 4608 16B chunks, swizzled slot^= (row&7)
    const unsigned short* wsrc = Wbf + (size_t)mh * 144 * 256;
#pragma unroll
    for (int p = 0; p < 9; ++p) {
      const int id = p * 512 + tid;
      const int row = id >> 5, slot = id & 31;
      *(f32x4*)(Wsm + row * 512 + ((slot ^ (row & 7)) << 4)) =
          *(const f32x4*)(wsrc + row * 256 + slot * 8);
    }
  }
  { // stage x tile: 4x4 register transpose, fp32 -> bf16, same swizzle
    const float* xb = x + (size_t)b * C_ * N_ + n0;
#pragma unroll
    for (int pass = 0; pass < 4; ++pass) {
      const int id = pass * 512 + tid;
      const int nq = id & 31, kq = id >> 5;   // n=4nq, k=4kq
      const int k = kq << 2, nn = nq << 2;
      f32x4 r0 = *(const f32x4*)&xb[(size_t)(k + 0) * N_ + nn];
      f32x4 r1 = *(const f32x4*)&xb[(size_t)(k + 1) * N_ + nn];
      f32x4 r2 = *(const f32x4*)&xb[(size_t)(k + 2) * N_ + nn];
      f32x4 r3 = *(const f32x4*)&xb[(size_t)(k + 3) * N_ + nn];
#pragma unroll
      for (int j = 0; j < 4; ++j) {
        short4v p;
        p[0] = (short)f2bf(r0[j]); p[1] = (short)f2bf(r1[j]);
        p[2] = (short)f2bf(r2[j]); p[3] = (short)f2bf(r3[j]);
        const int row = nn + j;
        *(short4v*)(xsm + row * 512 + (((k >> 3) ^ (row & 7)) << 4) + ((k & 7) << 1)) = p;
      }
    }
  }
  __syncthreads();

  // ---- MFMA: wave w owns local frag w (16 m-rows); wave 0 also frag 8
  const bool two = (w == 0);
  f32x4 acc[2][8];
#pragma unroll
  for (int s = 0; s < 2; ++s)
#pragma unroll
    for (int nf = 0; nf < 8; ++nf) acc[s][nf] = (f32x4){0.f, 0.f, 0.f, 0.f};

#pragma unroll
  for (int kk = 0; kk < 8; ++kk) {
    const int soff = ((((kk << 2) + g) ^ (li & 7)) << 4);
    bf16x8 bx[8];
#pragma unroll
    for (int nf = 0; nf < 8; ++nf)
      bx[nf] = *(const bf16x8*)(xsm + (nf * 16 + li) * 512 + soff);
    bf16x8 a0 = *(const bf16x8*)(Wsm + (size_t)(w * 16 + li) * 512 + soff);
#pragma unroll
    for (int nf = 0; nf < 8; ++nf)
      acc[0][nf] = __builtin_amdgcn_mfma_f32_16x16x32_bf16(a0, bx[nf], acc[0][nf], 0, 0, 0);
    if (two) {
      bf16x8 a1 = *(const bf16x8*)(Wsm + (size_t)(8 * 16 + li) * 512 + soff);
#pragma unroll
      for (int nf = 0; nf < 8; ++nf)
        acc[1][nf] = __builtin_amdgcn_mfma_f32_16x16x32_bf16(a1, bx[nf], acc[1][nf], 0, 0, 0);
    }
  }
  __syncthreads();   // xsm reads done; overlay below

  // ---- epilogue: bias + bf16 into overlay, then coalesced stores
  unsigned short* vsm = (unsigned short*)xsm;            // [<=144][128] (36 KB max)
  unsigned short* qsm = (unsigned short*)(xsm + 36864);  // [128][16]
  unsigned short* ksm = (unsigned short*)(xsm + 40960);  // [128][16]
#pragma unroll
  for (int s = 0; s < 2; ++s) {
    if (s == 1 && !two) break;
    const int gf = mh * 9 + (s == 0 ? w : 8);            // global m-frag 0..17
    f32x4 bb;
    if (gf == 0)      bb = *(const f32x4*)&bq[4 * g];
    else if (gf == 1) bb = *(const f32x4*)&bk[4 * g];
    else              bb = *(const f32x4*)&bv[(gf - 2) * 16 + 4 * g];
    if (gf >= 2) {
      const int vb16 = (gf - 2 - mh * 7) << 4;           // local v-row base
#pragma unroll
      for (int r = 0; r < 4; ++r)
#pragma unroll
        for (int nf = 0; nf < 8; ++nf)
          vsm[(vb16 + 4 * g + r) * 128 + nf * 16 + li] = f2bf(acc[s][nf][r] + bb[r]);
    } else {
      unsigned short* t = (gf == 0) ? qsm : ksm;
#pragma unroll
      for (int nf = 0; nf < 8; ++nf)
#pragma unroll
        for (int r = 0; r < 4; ++r)
          t[(nf * 16 + li) * 16 + 4 * g + r] = f2bf(acc[s][nf][r] + bb[r]);
    }
  }
  __syncthreads();

  const int nchunk = (mh ? 144 : 112) * 16;              // 16B chunks of v
#pragma unroll
  for (int p = 0; p < 5; ++p) {
    const int id = p * 512 + tid;
    if (id < nchunk) {
      const int vr = id >> 4, off = id & 15;
      const int c = mh * 112 + vr;
      *(f32x4*)(vbf + ((size_t)b * C_ + c) * N_ + n0 + off * 8) =
          *(const f32x4*)(vsm + vr * 128 + off * 8);
    }
  }
  if (mh == 0) {                                         // q/k: 128 rows x 2 halves each
    const unsigned short* ssm = (tid < 256) ? qsm : ksm;
    unsigned short* dst = (tid < 256) ? qT : kT;
    const int t2 = tid & 255;
    const int n = t2 >> 1, half = t2 & 1;
    *(f32x4*)(dst + ((size_t)b * N_ + n0 + n) * 24 + half * 8) =
        *(const f32x4*)(ssm + n * 16 + half * 8);
  }
}

// ---------------------------------------------------------------- K2: fused attention
__global__ __launch_bounds__(512, 4) void attn_fused_kernel(
    const float* __restrict__ x, const unsigned short* __restrict__ qT,
    const unsigned short* __restrict__ kT, const unsigned short* __restrict__ vbf,
    const float* __restrict__ sgamma, float* __restrict__ out) {
  // LDS: Pl0[64m][128B] | Pl1 | (epilogue overlay Tl[128][64] f32) | denl
  __shared__ __align__(16) char smem[33312];
  char* Pl0 = smem;
  char* Pl1 = smem + 8192;
  float* Tl   = (float*)smem;
  float* denl = (float*)(smem + 32768);

  const int tid = threadIdx.x;
  const int ln = tid & 63, w = tid >> 6;
  const int g  = ln >> 4, li = ln & 15;
  const int fmS  = w >> 1;            // S-phase m-frag
  const int fnS0 = (w & 1) << 1;      // S-phase first n-frag
  const int wcq  = w & 3;             // PV c-quad (32 rows)
  const int wmh  = w >> 2;            // PV m-half (32 cols)

  // bijective XCD chunking: 512 blocks, 64 per XCD; each batch -> 2 XCDs
  const int orig = blockIdx.x;
  const int L    = ((orig & 7) << 6) + (orig >> 3);
  const int b    = L >> 7;
  const int rem  = L & 127;
  const int m0   = (rem >> 1) << 6;
  const int ch   = rem & 1;           // c-half: rows [128*ch, 128*ch+128)

  const char* qbase = (const char*)qT + (size_t)b * N_ * 48;
  const char* kbase = (const char*)kT + (size_t)b * N_ * 48;
  const char* vb    = (const char*)vbf + (size_t)b * C_ * N_ * 2;

  const bf16x8 Z8 = (bf16x8){0, 0, 0, 0, 0, 0, 0, 0};

  // persistent k B-fragment (col m = fmS*16+li, ch = g*8+e; g>=2 zero-pad)
  const bf16x8 kfrag = (g < 2)
      ? *(const bf16x8*)(kbase + (size_t)(m0 + fmS * 16 + li) * 48 + g * 16) : Z8;

  const char* qp0 = qbase + (size_t)(fnS0 * 16 + li) * 48 + g * 16;
  const char* vp0 = vb + (size_t)(ch * 128 + wcq * 32 + li) * (N_ * 2) + g * 16;

  f32x4 oacc[2][2];
#pragma unroll
  for (int cf = 0; cf < 2; ++cf)
#pragma unroll
    for (int mf = 0; mf < 2; ++mf) oacc[cf][mf] = (f32x4){0.f, 0.f, 0.f, 0.f};
  float den_part = 0.f;

  bf16x8 qA0, qA1, qB0, qB1;
  bf16x8 vA[2][2], vB[2][2];

  qA0 = (g < 2) ? *(const bf16x8*)(qp0) : Z8;
  qA1 = (g < 2) ? *(const bf16x8*)(qp0 + 768) : Z8;
#pragma unroll
  for (int cf = 0; cf < 2; ++cf)
#pragma unroll
    for (int ks = 0; ks < 2; ++ks)
      vA[cf][ks] = *(const bf16x8*)(vp0 + (size_t)cf * (16 * N_ * 2) + ks * 64);

#define TILE(CQ0, CQ1, CV, NQ0, NQ1, NV, PBUF, T) do {                               \
    const size_t tnb = (size_t)(((T) + 1) & 63);                                     \
    NQ0 = (g < 2) ? *(const bf16x8*)(qp0 + tnb * 3072) : Z8;                         \
    NQ1 = (g < 2) ? *(const bf16x8*)(qp0 + tnb * 3072 + 768) : Z8;                   \
    _Pragma("unroll")                                                                \
    for (int cf = 0; cf < 2; ++cf)                                                   \
      _Pragma("unroll")                                                              \
      for (int ks = 0; ks < 2; ++ks)                                                 \
        NV[cf][ks] = *(const bf16x8*)(vp0 + tnb * 128 +                              \
                                      (size_t)cf * (16 * N_ * 2) + ks * 64);         \
    { /* S phase: frags (fnS0, fmS), (fnS0+1, fmS) */                                \
      const int mrow = fmS * 16 + li;                                                \
      f32x4 s0 = (f32x4){0.f, 0.f, 0.f, 0.f};                                        \
      s0 = __builtin_amdgcn_mfma_f32_16x16x32_bf16(CQ0, kfrag, s0, 0, 0, 0);         \
      float e0 = __expf(s0[0]), e1 = __expf(s0[1]);                                  \
      float e2 = __expf(s0[2]), e3 = __expf(s0[3]);                                  \
      den_part += (e0 + e1) + (e2 + e3);                                             \
      short4v pk0;                                                                   \
      pk0[0] = (short)f2bf(e0); pk0[1] = (short)f2bf(e1);                            \
      pk0[2] = (short)f2bf(e2); pk0[3] = (short)f2bf(e3);                            \
      *(short4v*)((PBUF) + mrow * 128 +                                              \
                  (((fnS0 << 5) + (g << 3)) ^ ((mrow & 7) << 4))) = pk0;             \
      f32x4 s1 = (f32x4){0.f, 0.f, 0.f, 0.f};                                        \
      s1 = __builtin_amdgcn_mfma_f32_16x16x32_bf16(CQ1, kfrag, s1, 0, 0, 0);         \
      float f0 = __expf(s1[0]), f1 = __expf(s1[1]);                                  \
      float f2v = __expf(s1[2]), f3 = __expf(s1[3]);                                 \
      den_part += (f0 + f1) + (f2v + f3);                                            \
      short4v pk1;                                                                   \
      pk1[0] = (short)f2bf(f0); pk1[1] = (short)f2bf(f1);                            \
      pk1[2] = (short)f2bf(f2v); pk1[3] = (short)f2bf(f3);                           \
      *(short4v*)((PBUF) + mrow * 128 +                                              \
                  ((((fnS0 + 1) << 5) + (g << 3)) ^ ((mrow & 7) << 4))) = pk1;       \
    }                                                                                \
    asm volatile("s_waitcnt lgkmcnt(0)" ::: "memory");                               \
    __builtin_amdgcn_sched_barrier(0);                                               \
    __builtin_amdgcn_s_barrier();                                                    \
    __builtin_amdgcn_sched_barrier(0);                                               \
    __builtin_amdgcn_s_setprio(1);                                                   \
    _Pragma("unroll")                                                                \
    for (int ks = 0; ks < 2; ++ks) {                                                 \
      bf16x8 bfr[2];                                                                 \
      _Pragma("unroll")                                                              \
      for (int mf = 0; mf < 2; ++mf) {                                               \
        const int mr = (2 * wmh + mf) * 16 + li;                                     \
        bfr[mf] = *(const bf16x8*)((PBUF) + mr * 128 +                               \
                                   (((ks << 6) + (g << 4)) ^ ((mr & 7) << 4)));      \
      }                                                                              \
      _Pragma("unroll")                                                              \
      for (int cf = 0; cf < 2; ++cf)                                                 \
        _Pragma("unroll")                                                            \
        for (int mf = 0; mf < 2; ++mf)                                               \
          oacc[cf][mf] = __builtin_amdgcn_mfma_f32_16x16x32_bf16(                    \
              CV[cf][ks], bfr[mf], oacc[cf][mf], 0, 0, 0);                           \
    }                                                                                \
    __builtin_amdgcn_s_setprio(0);                                                   \
  } while (0)

  for (int tt = 0; tt < NT / 2; ++tt) {
    TILE(qA0, qA1, vA, qB0, qB1, vB, Pl0, 2 * tt);
    TILE(qB0, qB1, vB, qA0, qA1, vA, Pl1, 2 * tt + 1);
  }
#undef TILE

  // ---- den reduce (full den per block; duplicated across c-halves)
  float d = den_part;
  d += __shfl_xor(d, 16, 64);
  d += __shfl_xor(d, 32, 64);
  if (ln < 16) denl[w * 16 + li] = d;
  __syncthreads();                     // all PV reads done; denl visible

  float rden[2];
#pragma unroll
  for (int mf = 0; mf < 2; ++mf) {
    const int fmg = 2 * wmh + mf;
    rden[mf] = 1.f / (denl[(2 * fmg) * 16 + li] + denl[(2 * fmg + 1) * 16 + li]);
  }
  const float gam = sgamma[0];

  // ---- epilogue: Tl[128 c][64 m] overlay -> coalesced out = x + gamma*num/den
#pragma unroll
  for (int cf = 0; cf < 2; ++cf)
#pragma unroll
    for (int mf = 0; mf < 2; ++mf)
#pragma unroll
      for (int r = 0; r < 4; ++r)
        Tl[(wcq * 32 + cf * 16 + 4 * g + r) * 64 + wmh * 32 + mf * 16 + li] =
            oacc[cf][mf][r] * rden[mf];
  __syncthreads();
#pragma unroll
  for (int p = 0; p < 4; ++p) {
    const int id = p * 512 + tid;
    const int cl = id >> 4, mo = (id & 15) << 2;
    const size_t gi = ((size_t)b * C_ + ch * 128 + cl) * N_ + m0 + mo;
    const float4 xa = *(const float4*)&x[gi];
    const f32x4  ov = *(const f32x4*)&Tl[cl * 64 + mo];
    float4 rr;
    rr.x = xa.x + gam * ov[0];
    rr.y = xa.y + gam * ov[1];
    rr.z = xa.z + gam * ov[2];
    rr.w = xa.w + gam * ov[3];
    *(float4*)&out[gi] = rr;
  }
}

// ---------------------------------------------------------------- launch
extern "C" void kernel_launch(void* const* d_in, const int* in_sizes, int n_in,
                              void* d_out, int out_size, void* d_ws, size_t ws_size,
                              hipStream_t stream) {
  const float* x     = (const float*)d_in[0];
  const float* Wq    = (const float*)d_in[1];
  const float* bq    = (const float*)d_in[2];
  const float* Wk    = (const float*)d_in[3];
  const float* bk    = (const float*)d_in[4];
  const float* Wv    = (const float*)d_in[5];
  const float* bv    = (const float*)d_in[6];
  const float* gamma = (const float*)d_in[7];
  float* out = (float*)d_out;

  unsigned short* qTg = (unsigned short*)d_ws;              // [B][N][24] (48B rows)
  unsigned short* kTg = qTg + (size_t)B_ * N_ * 24;         // [B][N][24]
  unsigned short* vbf = kTg + (size_t)B_ * N_ * 24;         // [B][C][N]
  unsigned short* Wbf = vbf + (size_t)B_ * C_ * N_;         // [288][256]

  cast_w_kernel<<<36, 256, 0, stream>>>(Wq, Wk, Wv, Wbf);
  proj_fused_kernel<<<dim3(32, 2, 4), 512, 0, stream>>>(x, Wbf, bq, bk, bv, qTg, kTg, vbf);
  attn_fused_kernel<<<512, 512, 0, stream>>>(x, qTg, kTg, vbf, gamma, out);
}

// Round 6
// 174.583 us; speedup vs baseline: 1.2639x; 1.2639x over previous
//
#include <hip/hip_runtime.h>
#include <hip/hip_bf16.h>

// SAGAN self-attention, B=4, C=256, N=4096, Cqk=16, fp32 I/O.
//  K0 cast_w    : Wbf[288][256] bf16  (rows 0-15 Wq, 16-31 Wk, 32-287 Wv)
//  K1 proj_fused: grid (64 n-tiles x 3 m-thirds x 4 b), 256 thr. x-tile
//                 [64n][256k] bf16 staged swizzled in LDS (32 KB); W-frags from
//                 L2; wave w owns n-frag w for 6 m-frags. Overlay epilogue ->
//                 coalesced qT/kT[b][n][24] + vbf[b][c][n] stores.
//  K2 attn      : (R4 structure, verbatim) per (b, 64-m): loop 64 n-tiles:
//                 S = q^T k (MFMA), e=exp(S); den += sum e; num += V @ e.
//                 V,q global->reg prefetch (L2-resident); only P in LDS
//                 (dbuf, XOR-swizzled); one raw s_barrier per tile.
//                 out = x + gamma*num/den.

constexpr int B_ = 4;
constexpr int C_ = 256;
constexpr int N_ = 4096;
constexpr int NT = 64;

typedef short   bf16x8  __attribute__((ext_vector_type(8)));
typedef short   short4v __attribute__((ext_vector_type(4)));
typedef unsigned short ushort8v __attribute__((ext_vector_type(8)));
typedef float   f32x4   __attribute__((ext_vector_type(4)));

__device__ __forceinline__ unsigned short f2bf(float f) {
  __hip_bfloat16 h = __float2bfloat16(f);
  return *reinterpret_cast<unsigned short*>(&h);
}

// ---------------------------------------------------------------- K0: W -> bf16
__global__ __launch_bounds__(256) void cast_w_kernel(
    const float* __restrict__ Wq, const float* __restrict__ Wk,
    const float* __restrict__ Wv, unsigned short* __restrict__ Wbf) {
  const int f = (blockIdx.x * 256 + threadIdx.x) * 8;
  const float* src;
  if (f < 4096)      src = Wq + f;
  else if (f < 8192) src = Wk + (f - 4096);
  else               src = Wv + (f - 8192);
  f32x4 a = *(const f32x4*)src;
  f32x4 c = *(const f32x4*)(src + 4);
  ushort8v o;
#pragma unroll
  for (int e = 0; e < 4; ++e) { o[e] = f2bf(a[e]); o[4 + e] = f2bf(c[e]); }
  *(ushort8v*)&Wbf[f] = o;
}

// ---------------------------------------------------------------- K1: fused projections v3
__global__ __launch_bounds__(256) void proj_fused_kernel(
    const float* __restrict__ x, const unsigned short* __restrict__ Wbf,
    const float* __restrict__ bq, const float* __restrict__ bk,
    const float* __restrict__ bv,
    unsigned short* __restrict__ qT, unsigned short* __restrict__ kT,
    unsigned short* __restrict__ vbf) {
  __shared__ __align__(16) char smem[32768];   // xsm [64 n][256 k] bf16 swizzled
  const int tid = threadIdx.x;
  const int n0    = blockIdx.x << 6;
  const int third = blockIdx.y;                // m rows [96*third, 96*third+96)
  const int b     = blockIdx.z;
  const int ln = tid & 63, w = tid >> 6;       // 4 waves
  const int g  = ln >> 4, li = ln & 15;

  { // stage x tile: 4x4 register transpose, fp32 -> bf16, XOR-swizzled
    const float* xb = x + (size_t)b * C_ * N_ + n0;
#pragma unroll
    for (int pass = 0; pass < 4; ++pass) {
      const int id = pass * 256 + tid;         // 0..1023
      const int nq = id & 15, kq = id >> 4;    // n = 4nq, k = 4kq
      const int k = kq << 2, nn = nq << 2;
      f32x4 r0 = *(const f32x4*)&xb[(size_t)(k + 0) * N_ + nn];
      f32x4 r1 = *(const f32x4*)&xb[(size_t)(k + 1) * N_ + nn];
      f32x4 r2 = *(const f32x4*)&xb[(size_t)(k + 2) * N_ + nn];
      f32x4 r3 = *(const f32x4*)&xb[(size_t)(k + 3) * N_ + nn];
#pragma unroll
      for (int j = 0; j < 4; ++j) {
        short4v p;
        p[0] = (short)f2bf(r0[j]); p[1] = (short)f2bf(r1[j]);
        p[2] = (short)f2bf(r2[j]); p[3] = (short)f2bf(r3[j]);
        const int row = nn + j;
        *(short4v*)(smem + row * 512 + (((k >> 3) ^ (row & 7)) << 4) + ((k & 7) << 1)) = p;
      }
    }
  }
  __syncthreads();

  // ---- MFMA: wave w owns n-frag w; 6 m-frags of this third from L2
  f32x4 acc[6];
#pragma unroll
  for (int mf = 0; mf < 6; ++mf) acc[mf] = (f32x4){0.f, 0.f, 0.f, 0.f};
  const char* wb = (const char*)Wbf + (size_t)third * 96 * 512;
#pragma unroll
  for (int kk = 0; kk < 8; ++kk) {
    const int soff = ((((kk << 2) + g) ^ (li & 7)) << 4);
    bf16x8 bx = *(const bf16x8*)(smem + (w * 16 + li) * 512 + soff);
#pragma unroll
    for (int mf = 0; mf < 6; ++mf) {
      bf16x8 af = *(const bf16x8*)(wb + (size_t)(mf * 16 + li) * 512 + kk * 64 + g * 16);
      acc[mf] = __builtin_amdgcn_mfma_f32_16x16x32_bf16(af, bx, acc[mf], 0, 0, 0);
    }
  }
  __syncthreads();   // xsm reads done; overlay below

  // ---- epilogue into overlay: vsm[<=96][64] | qsm[64][16] | ksm[64][16]
  unsigned short* vsm = (unsigned short*)smem;             // 12 KB max
  unsigned short* qsm = (unsigned short*)(smem + 12288);   //  2 KB
  unsigned short* ksm = (unsigned short*)(smem + 14336);   //  2 KB
#pragma unroll
  for (int mf = 0; mf < 6; ++mf) {
    const int gf = third * 6 + mf;                         // global m-frag 0..17
    f32x4 bb;
    if (gf == 0)      bb = *(const f32x4*)&bq[4 * g];
    else if (gf == 1) bb = *(const f32x4*)&bk[4 * g];
    else              bb = *(const f32x4*)&bv[(gf - 2) * 16 + 4 * g];
    if (gf >= 2) {
      const int cL = (third == 0 ? (mf - 2) : mf) << 4;    // local v row base
#pragma unroll
      for (int r = 0; r < 4; ++r)
        vsm[(cL + 4 * g + r) * 64 + w * 16 + li] = f2bf(acc[mf][r] + bb[r]);
    } else {
      unsigned short* t = (gf == 0) ? qsm : ksm;
#pragma unroll
      for (int r = 0; r < 4; ++r)
        t[(w * 16 + li) * 16 + 4 * g + r] = f2bf(acc[mf][r] + bb[r]);
    }
  }
  __syncthreads();

  // ---- coalesced stores
  const int vrows = (third == 0) ? 64 : 96;
  const int c0    = (third == 0) ? 0 : (third == 1 ? 64 : 160);
  const int nch   = vrows * 8;                             // 16B chunks (64 n = 128 B)
#pragma unroll
  for (int p = 0; p < 3; ++p) {
    const int id = p * 256 + tid;
    if (id < nch) {
      const int vr = id >> 3, off = id & 7;
      *(f32x4*)(vbf + ((size_t)b * C_ + c0 + vr) * N_ + n0 + off * 8) =
          *(const f32x4*)(vsm + vr * 64 + off * 8);
    }
  }
  if (third == 0) {   // q/k: 64 rows x 2 halves x 2 tensors = 256 chunks
    const unsigned short* ssm = (tid < 128) ? qsm : ksm;
    unsigned short* dst = (tid < 128) ? qT : kT;
    const int t2 = tid & 127;
    const int n = t2 >> 1, half = t2 & 1;
    *(f32x4*)(dst + ((size_t)b * N_ + n0 + n) * 24 + half * 8) =
        *(const f32x4*)(ssm + n * 16 + half * 8);
  }
}

// ---------------------------------------------------------------- K2: fused attention (R4)
__global__ __launch_bounds__(512) void attn_fused_kernel(
    const float* __restrict__ x, const unsigned short* __restrict__ qT,
    const unsigned short* __restrict__ kT, const unsigned short* __restrict__ vbf,
    const float* __restrict__ sgamma, float* __restrict__ out) {
  // LDS: Pl0[64m][128B] | Pl1 | (epilogue overlay Tl[128][64] f32) | denl
  __shared__ __align__(16) char smem[33312];
  char* Pl0 = smem;
  char* Pl1 = smem + 8192;
  float* Tl   = (float*)smem;
  float* denl = (float*)(smem + 32768);

  const int tid = threadIdx.x;
  const int ln = tid & 63, w = tid >> 6;
  const int g  = ln >> 4, li = ln & 15;
  const int fmS  = w >> 1;            // S-phase m-frag
  const int fnS0 = (w & 1) << 1;      // S-phase first n-frag

  // XCD swizzle: 256 blocks, 8 XCDs
  const int orig = blockIdx.x;
  const int swz  = ((orig & 7) << 5) + (orig >> 3);
  const int b  = swz >> 6;
  const int m0 = (swz & 63) << 6;

  const char* qbase = (const char*)qT + (size_t)b * N_ * 48;
  const char* kbase = (const char*)kT + (size_t)b * N_ * 48;
  const char* vb    = (const char*)vbf + (size_t)b * C_ * N_ * 2;

  const bf16x8 Z8 = (bf16x8){0, 0, 0, 0, 0, 0, 0, 0};

  // persistent k B-fragment (col m = fmS*16+li, ch = g*8+e; g>=2 zero-pad)
  const bf16x8 kfrag = (g < 2)
      ? *(const bf16x8*)(kbase + (size_t)(m0 + fmS * 16 + li) * 48 + g * 16) : Z8;

  const char* qp0 = qbase + (size_t)(fnS0 * 16 + li) * 48 + g * 16;
  const char* vp0 = vb + (size_t)(w * 32 + li) * (N_ * 2) + g * 16;

  f32x4 oacc[2][4];
#pragma unroll
  for (int c2 = 0; c2 < 2; ++c2)
#pragma unroll
    for (int mf = 0; mf < 4; ++mf) oacc[c2][mf] = (f32x4){0.f, 0.f, 0.f, 0.f};
  float den_part = 0.f;

  bf16x8 qA0, qA1, qB0, qB1;
  bf16x8 vA[2][2], vB[2][2];

  qA0 = (g < 2) ? *(const bf16x8*)(qp0) : Z8;
  qA1 = (g < 2) ? *(const bf16x8*)(qp0 + 768) : Z8;
#pragma unroll
  for (int c2 = 0; c2 < 2; ++c2)
#pragma unroll
    for (int ks = 0; ks < 2; ++ks)
      vA[c2][ks] = *(const bf16x8*)(vp0 + (size_t)c2 * (16 * N_ * 2) + ks * 64);

#define TILE(CQ0, CQ1, CV, NQ0, NQ1, NV, PBUF, T) do {                               \
    const size_t tnb = (size_t)(((T) + 1) & 63);                                     \
    NQ0 = (g < 2) ? *(const bf16x8*)(qp0 + tnb * 3072) : Z8;                         \
    NQ1 = (g < 2) ? *(const bf16x8*)(qp0 + tnb * 3072 + 768) : Z8;                   \
    _Pragma("unroll")                                                                \
    for (int c2 = 0; c2 < 2; ++c2)                                                   \
      _Pragma("unroll")                                                              \
      for (int ks = 0; ks < 2; ++ks)                                                 \
        NV[c2][ks] = *(const bf16x8*)(vp0 + tnb * 128 +                              \
                                      (size_t)c2 * (16 * N_ * 2) + ks * 64);         \
    { /* S phase: frags (fnS0, fmS), (fnS0+1, fmS) */                                \
      const int mrow = fmS * 16 + li;                                                \
      f32x4 s0 = (f32x4){0.f, 0.f, 0.f, 0.f};                                        \
      s0 = __builtin_amdgcn_mfma_f32_16x16x32_bf16(CQ0, kfrag, s0, 0, 0, 0);         \
      float e0 = __expf(s0[0]), e1 = __expf(s0[1]);                                  \
      float e2 = __expf(s0[2]), e3 = __expf(s0[3]);                                  \
      den_part += (e0 + e1) + (e2 + e3);                                             \
      short4v pk0;                                                                   \
      pk0[0] = (short)f2bf(e0); pk0[1] = (short)f2bf(e1);                            \
      pk0[2] = (short)f2bf(e2); pk0[3] = (short)f2bf(e3);                            \
      *(short4v*)((PBUF) + mrow * 128 +                                              \
                  (((fnS0 << 5) + (g << 3)) ^ ((mrow & 7) << 4))) = pk0;             \
      f32x4 s1 = (f32x4){0.f, 0.f, 0.f, 0.f};                                        \
      s1 = __builtin_amdgcn_mfma_f32_16x16x32_bf16(CQ1, kfrag, s1, 0, 0, 0);         \
      float f0 = __expf(s1[0]), f1 = __expf(s1[1]);                                  \
      float f2v = __expf(s1[2]), f3 = __expf(s1[3]);                                 \
      den_part += (f0 + f1) + (f2v + f3);                                            \
      short4v pk1;                                                                   \
      pk1[0] = (short)f2bf(f0); pk1[1] = (short)f2bf(f1);                            \
      pk1[2] = (short)f2bf(f2v); pk1[3] = (short)f2bf(f3);                           \
      *(short4v*)((PBUF) + mrow * 128 +                                              \
                  ((((fnS0 + 1) << 5) + (g << 3)) ^ ((mrow & 7) << 4))) = pk1;       \
    }                                                                                \
    asm volatile("s_waitcnt lgkmcnt(0)" ::: "memory");                               \
    __builtin_amdgcn_sched_barrier(0);                                               \
    __builtin_amdgcn_s_barrier();                                                    \
    __builtin_amdgcn_sched_barrier(0);                                               \
    _Pragma("unroll")                                                                \
    for (int ks = 0; ks < 2; ++ks) {                                                 \
      bf16x8 bfr[4];                                                                 \
      _Pragma("unroll")                                                              \
      for (int mf = 0; mf < 4; ++mf) {                                               \
        const int mr = mf * 16 + li;                                                 \
        bfr[mf] = *(const bf16x8*)((PBUF) + mr * 128 +                               \
                                   (((ks << 6) + (g << 4)) ^ ((mr & 7) << 4)));      \
      }                                                                              \
      _Pragma("unroll")                                                              \
      for (int c2 = 0; c2 < 2; ++c2)                                                 \
        _Pragma("unroll")                                                            \
        for (int mf = 0; mf < 4; ++mf)                                               \
          oacc[c2][mf] = __builtin_amdgcn_mfma_f32_16x16x32_bf16(                    \
              CV[c2][ks], bfr[mf], oacc[c2][mf], 0, 0, 0);                           \
    }                                                                                \
  } while (0)

  for (int tt = 0; tt < NT / 2; ++tt) {
    TILE(qA0, qA1, vA, qB0, qB1, vB, Pl0, 2 * tt);
    TILE(qB0, qB1, vB, qA0, qA1, vA, Pl1, 2 * tt + 1);
  }
#undef TILE

  // ---- den reduce + epilogue
  float d = den_part;
  d += __shfl_xor(d, 16, 64);
  d += __shfl_xor(d, 32, 64);
  if (ln < 16) denl[w * 16 + li] = d;
  __syncthreads();                              // all waves past loop; denl visible

  float rden[4];
#pragma unroll
  for (int mf = 0; mf < 4; ++mf)
    rden[mf] = 1.f / (denl[(2 * mf) * 16 + li] + denl[(2 * mf + 1) * 16 + li]);
  const float gam = sgamma[0];

#pragma unroll
  for (int h = 0; h < 2; ++h) {
    __syncthreads();                            // Tl region free
    if ((w >> 2) == h) {
#pragma unroll
      for (int c2 = 0; c2 < 2; ++c2)
#pragma unroll
        for (int mf = 0; mf < 4; ++mf)
#pragma unroll
          for (int r = 0; r < 4; ++r)
            Tl[((w & 3) * 32 + c2 * 16 + 4 * g + r) * 64 + mf * 16 + li] =
                oacc[c2][mf][r] * rden[mf];
    }
    __syncthreads();
#pragma unroll
    for (int p = 0; p < 4; ++p) {
      const int clocal = (p << 5) + (tid >> 4);
      const int c  = (h << 7) + clocal;
      const int mo = (tid & 15) << 2;
      const size_t gi = ((size_t)b * C_ + c) * N_ + m0 + mo;
      const float4 xa = *(const float4*)&x[gi];
      const f32x4  ov = *(const f32x4*)&Tl[clocal * 64 + mo];
      float4 rr;
      rr.x = xa.x + gam * ov[0];
      rr.y = xa.y + gam * ov[1];
      rr.z = xa.z + gam * ov[2];
      rr.w = xa.w + gam * ov[3];
      *(float4*)&out[gi] = rr;
    }
  }
}

// ---------------------------------------------------------------- launch
extern "C" void kernel_launch(void* const* d_in, const int* in_sizes, int n_in,
                              void* d_out, int out_size, void* d_ws, size_t ws_size,
                              hipStream_t stream) {
  const float* x     = (const float*)d_in[0];
  const float* Wq    = (const float*)d_in[1];
  const float* bq    = (const float*)d_in[2];
  const float* Wk    = (const float*)d_in[3];
  const float* bk    = (const float*)d_in[4];
  const float* Wv    = (const float*)d_in[5];
  const float* bv    = (const float*)d_in[6];
  const float* gamma = (const float*)d_in[7];
  float* out = (float*)d_out;

  unsigned short* qTg = (unsigned short*)d_ws;              // [B][N][24] (48B rows)
  unsigned short* kTg = qTg + (size_t)B_ * N_ * 24;         // [B][N][24]
  unsigned short* vbf = kTg + (size_t)B_ * N_ * 24;         // [B][C][N]
  unsigned short* Wbf = vbf + (size_t)B_ * C_ * N_;         // [288][256]

  cast_w_kernel<<<36, 256, 0, stream>>>(Wq, Wk, Wv, Wbf);
  proj_fused_kernel<<<dim3(64, 3, 4), 256, 0, stream>>>(x, Wbf, bq, bk, bv, qTg, kTg, vbf);
  attn_fused_kernel<<<256, 512, 0, stream>>>(x, qTg, kTg, vbf, gamma, out);
}